// Round 6
// baseline (82.457 us; speedup 1.0000x reference)
//
#include <hip/hip_runtime.h>

#define NCH 256
#define ROIS_ELEMS 50176000              // 800*7*7*1280

typedef float vf4 __attribute__((ext_vector_type(4)));

// One wave handles one (box n, level l, row py): 7 cells x 256 channels.
// 800 boxes * 5 levels * 7 rows = 28000 waves; 4 waves/block -> 7000 blocks.
// R6 = R3 verbatim except: plain stores instead of nontemporal (HBM write-path A/B).
__global__ __launch_bounds__(256) void roi_row_kernel(
    const float* __restrict__ boxes,   // [800,4] image-space (y1,x1,y2,x2)
    const float* __restrict__ fm0,
    const float* __restrict__ fm1,
    const float* __restrict__ fm2,
    const float* __restrict__ fm3,
    const float* __restrict__ fm4,
    float* __restrict__ out,           // [800,7,7,1280]
    float* __restrict__ out_ids)       // [800] written as float
{
    const int wave = threadIdx.x >> 6;
    const int lane = threadIdx.x & 63;

    // XCD-chunked bijective swizzle: 7000 = 8 * 875 exactly.
    const int bswz = (blockIdx.x & 7) * 875 + (blockIdx.x >> 3);
    const int row  = bswz * 4 + wave;          // [0, 28000)

    const int n   = row / 35;                  // box index [0,800)
    const int rem = row - n * 35;
    const int l   = rem / 7;                   // level [0,5)
    const int py  = rem - l * 7;               // output row [0,7)

    const float* fm;
    switch (l) {
        case 0: fm = fm0; break;
        case 1: fm = fm1; break;
        case 2: fm = fm2; break;
        case 3: fm = fm3; break;
        default: fm = fm4; break;
    }
    const int H = 128 >> l;                    // square feature map
    const float Hm1 = (float)(H - 1);
    const float scale = (float)((8 << l) * (H - 1));   // exact in f32

    const int img = n / 100;
    const float y1 = boxes[n * 4 + 0];
    const float x1 = boxes[n * 4 + 1];
    const float y2 = boxes[n * 4 + 2];
    const float x2 = boxes[n * 4 + 3];

    // Replicate reference numerics (explicit rounding, no fp-contract).
    const float y1n = __fdiv_rn(y1, scale);
    const float y2n = __fdiv_rn(y2, scale);
    const float x1n = __fdiv_rn(x1, scale);
    const float x2n = __fdiv_rn(x2, scale);

    const float fy = __fdiv_rn((float)py, 6.0f);
    const float ys = __fmul_rn(__fadd_rn(y1n, __fmul_rn(__fsub_rn(y2n, y1n), fy)), Hm1);
    const bool  vy = (ys >= 0.0f) && (ys <= Hm1);
    const float y0f = floorf(ys);
    const float wy  = ys - y0f;
    const float owy = 1.0f - wy;
    const int y0  = (int)fminf(fmaxf(y0f,        0.0f), Hm1);
    const int y1i = (int)fminf(fmaxf(y0f + 1.0f, 0.0f), Hm1);

    const int rowTop = (img * H + y0 ) * H;
    const int rowBot = (img * H + y1i) * H;

    // Phase 1: per-px coords + scalarized (wave-uniform) element offsets.
    float wx_[7];
    bool  vx_[7];
    int oT0[7], oT1[7], oB0[7], oB1[7];
    #pragma unroll
    for (int px = 0; px < 7; ++px) {
        const float fx = __fdiv_rn((float)px, 6.0f);
        const float xs = __fmul_rn(__fadd_rn(x1n, __fmul_rn(__fsub_rn(x2n, x1n), fx)), Hm1);
        vx_[px] = (xs >= 0.0f) && (xs <= Hm1);
        const float x0f = floorf(xs);
        wx_[px] = xs - x0f;
        const int x0  = (int)fminf(fmaxf(x0f,        0.0f), Hm1);
        const int x1i = (int)fminf(fmaxf(x0f + 1.0f, 0.0f), Hm1);
        oT0[px] = __builtin_amdgcn_readfirstlane((rowTop + x0 ) * NCH);
        oT1[px] = __builtin_amdgcn_readfirstlane((rowTop + x1i) * NCH);
        oB0[px] = __builtin_amdgcn_readfirstlane((rowBot + x0 ) * NCH);
        oB1[px] = __builtin_amdgcn_readfirstlane((rowBot + x1i) * NCH);
    }

    // Phase 2: issue all 28 corner loads (1 KB each, coalesced) -> max MLP.
    vf4 v00[7], v01[7], v10[7], v11[7];
    #pragma unroll
    for (int px = 0; px < 7; ++px) {
        v00[px] = ((const vf4*)(fm + oT0[px]))[lane];
        v01[px] = ((const vf4*)(fm + oT1[px]))[lane];
        v10[px] = ((const vf4*)(fm + oB0[px]))[lane];
        v11[px] = ((const vf4*)(fm + oB1[px]))[lane];
    }

    // Phase 3: blend + plain store (A/B vs R3's nontemporal).
    float* obase = out + ((n * 7 + py) * 7) * 1280 + l * NCH;
    #pragma unroll
    for (int px = 0; px < 7; ++px) {
        const float wx  = wx_[px];
        const float owx = 1.0f - wx;
        vf4 r = (v00[px] * owx + v01[px] * wx) * owy
              + (v10[px] * owx + v11[px] * wx) * wy;
        if (!(vy && vx_[px])) { r = (vf4)0.0f; }
        ((vf4*)(obase + px * 1280))[lane] = r;
    }

    if (l == 0 && py == 0 && lane == 0) {
        out_ids[n] = (float)img;
    }
}

extern "C" void kernel_launch(void* const* d_in, const int* in_sizes, int n_in,
                              void* d_out, int out_size, void* d_ws, size_t ws_size,
                              hipStream_t stream) {
    const float* boxes = (const float*)d_in[0];
    const float* fm0   = (const float*)d_in[1];
    const float* fm1   = (const float*)d_in[2];
    const float* fm2   = (const float*)d_in[3];
    const float* fm3   = (const float*)d_in[4];
    const float* fm4   = (const float*)d_in[5];

    float* out     = (float*)d_out;
    float* out_ids = out + ROIS_ELEMS;

    roi_row_kernel<<<7000, 256, 0, stream>>>(boxes, fm0, fm1, fm2, fm3, fm4, out, out_ids);
}

// Round 7
// 66.089 us; speedup vs baseline: 1.2477x; 1.2477x over previous
//
#include <hip/hip_runtime.h>

#define NCH 256
#define ROIS_ELEMS 50176000              // 800*7*7*1280

typedef float vf4 __attribute__((ext_vector_type(4)));

// One wave per output cell (box n, py, px), covering ALL 5 levels:
// 20 corner loads (1 KB each), one contiguous 5120 B NT write burst per wave.
// 800*49 = 39200 waves; 4 waves/block -> 9800 blocks = 8 * 1225 (XCD=image).
__global__ __launch_bounds__(256) void roi_cell_kernel(
    const float* __restrict__ boxes,   // [800,4] image-space (y1,x1,y2,x2)
    const float* __restrict__ fm0,
    const float* __restrict__ fm1,
    const float* __restrict__ fm2,
    const float* __restrict__ fm3,
    const float* __restrict__ fm4,
    float* __restrict__ out,           // [800,7,7,1280]
    float* __restrict__ out_ids)       // [800] written as float
{
    const int wave = threadIdx.x >> 6;
    const int lane = threadIdx.x & 63;

    // XCD-chunked bijective swizzle: 9800 = 8 * 1225 exactly.
    const int bswz = (blockIdx.x & 7) * 1225 + (blockIdx.x >> 3);
    const int cell = bswz * 4 + wave;          // [0, 39200)

    const int n   = cell / 49;                 // box index [0,800)
    const int rem = cell - n * 49;
    const int py  = rem / 7;
    const int px  = rem - py * 7;

    const float* fms[5] = { fm0, fm1, fm2, fm3, fm4 };

    const int img = n / 100;
    const float y1 = boxes[n * 4 + 0];
    const float x1 = boxes[n * 4 + 1];
    const float y2 = boxes[n * 4 + 2];
    const float x2 = boxes[n * 4 + 3];

    const float fy = __fdiv_rn((float)py, 6.0f);
    const float fx = __fdiv_rn((float)px, 6.0f);

    // Phase 1: per-level coords (reference-exact numerics) + scalar offsets.
    float wy_[5], owy_[5], wx_[5], owx_[5];
    bool  vv_[5];
    int o00[5], o01[5], o10[5], o11[5];
    #pragma unroll
    for (int l = 0; l < 5; ++l) {
        const int   H    = 128 >> l;
        const float Hm1  = (float)(H - 1);
        const float scale = (float)((8 << l) * (H - 1));   // exact in f32

        const float y1n = __fdiv_rn(y1, scale);
        const float y2n = __fdiv_rn(y2, scale);
        const float x1n = __fdiv_rn(x1, scale);
        const float x2n = __fdiv_rn(x2, scale);

        const float ys = __fmul_rn(__fadd_rn(y1n, __fmul_rn(__fsub_rn(y2n, y1n), fy)), Hm1);
        const float xs = __fmul_rn(__fadd_rn(x1n, __fmul_rn(__fsub_rn(x2n, x1n), fx)), Hm1);
        vv_[l] = (ys >= 0.0f) && (ys <= Hm1) && (xs >= 0.0f) && (xs <= Hm1);

        const float y0f = floorf(ys);
        const float x0f = floorf(xs);
        wy_[l] = ys - y0f;  owy_[l] = 1.0f - wy_[l];
        wx_[l] = xs - x0f;  owx_[l] = 1.0f - wx_[l];

        const int y0  = (int)fminf(fmaxf(y0f,        0.0f), Hm1);
        const int y1i = (int)fminf(fmaxf(y0f + 1.0f, 0.0f), Hm1);
        const int x0  = (int)fminf(fmaxf(x0f,        0.0f), Hm1);
        const int x1i = (int)fminf(fmaxf(x0f + 1.0f, 0.0f), Hm1);

        const int rowT = (img * H + y0 ) * H;
        const int rowB = (img * H + y1i) * H;
        o00[l] = __builtin_amdgcn_readfirstlane((rowT + x0 ) * NCH);
        o01[l] = __builtin_amdgcn_readfirstlane((rowT + x1i) * NCH);
        o10[l] = __builtin_amdgcn_readfirstlane((rowB + x0 ) * NCH);
        o11[l] = __builtin_amdgcn_readfirstlane((rowB + x1i) * NCH);
    }

    // Phase 2: issue all 20 corner loads (1 KB each, coalesced) -> max MLP.
    vf4 v00[5], v01[5], v10[5], v11[5];
    #pragma unroll
    for (int l = 0; l < 5; ++l) {
        const float* fm = fms[l];
        v00[l] = ((const vf4*)(fm + o00[l]))[lane];
        v01[l] = ((const vf4*)(fm + o01[l]))[lane];
        v10[l] = ((const vf4*)(fm + o10[l]))[lane];
        v11[l] = ((const vf4*)(fm + o11[l]))[lane];
    }

    // Phase 3: blend + one contiguous 5120 B NT write burst (5 x 1 KB).
    float* obase = out + cell * 1280;
    #pragma unroll
    for (int l = 0; l < 5; ++l) {
        vf4 r = (v00[l] * owx_[l] + v01[l] * wx_[l]) * owy_[l]
              + (v10[l] * owx_[l] + v11[l] * wx_[l]) * wy_[l];
        if (!vv_[l]) { r = (vf4)0.0f; }
        __builtin_nontemporal_store(r, ((vf4*)(obase + l * NCH)) + lane);
    }

    if (rem == 0 && lane == 0) {
        out_ids[n] = (float)img;
    }
}

extern "C" void kernel_launch(void* const* d_in, const int* in_sizes, int n_in,
                              void* d_out, int out_size, void* d_ws, size_t ws_size,
                              hipStream_t stream) {
    const float* boxes = (const float*)d_in[0];
    const float* fm0   = (const float*)d_in[1];
    const float* fm1   = (const float*)d_in[2];
    const float* fm2   = (const float*)d_in[3];
    const float* fm3   = (const float*)d_in[4];
    const float* fm4   = (const float*)d_in[5];

    float* out     = (float*)d_out;
    float* out_ids = out + ROIS_ELEMS;

    roi_cell_kernel<<<9800, 256, 0, stream>>>(boxes, fm0, fm1, fm2, fm3, fm4, out, out_ids);
}